// Round 5
// baseline (215.899 us; speedup 1.0000x reference)
//
#include <hip/hip_runtime.h>

#define GRIDN   16
#define KMAX    32
#define NPER    2048
#define DFEAT   256
#define RCELLS  256     // GRIDN*GRIDN
#define XYS     35      // ints per xy row (3 header + 32 inds)

__device__ __forceinline__ void add4(float4& a, const float4& b) {
    a.x += b.x; a.y += b.y; a.z += b.z; a.w += b.w;
}

// ---------------------------------------------------------------------------
// Phase 1: one wave = one xy row. Header+indices in SGPRs via readlane;
// 16 unconditional float4 gathers per round (masked -> row 0, L1-hot),
// second round behind a wave-uniform scalar branch. No LDS, no barriers.
// Writes cell-major ws[b][cell][d] (contiguous 1KB per row).
// ---------------------------------------------------------------------------
__global__ __launch_bounds__(256, 6) void spp_pool_phase1(
    const float* __restrict__ F,     // (B*NPER, DFEAT)
    const int*   __restrict__ xy,    // (B*NPER, XYS)
    float*       __restrict__ ws,    // (B, RCELLS, DFEAT)
    int B)
{
    int bx = blockIdx.x;
    int b, chunk;
    if ((B & 7) == 0) {
        // batch-major per XCD: XCD owns B/8 whole batches -> L2 locality
        int xcd = bx & 7;
        int s   = bx >> 3;               // per-XCD sequence
        b     = xcd * (B >> 3) + (s >> 6);
        chunk = s & 63;                  // 64 chunks x 4 rows per batch
    } else {
        b     = bx >> 6;
        chunk = bx & 63;
    }

    int tid  = threadIdx.x;
    int wv   = tid >> 6;
    int lane = tid & 63;
    int r    = chunk * 4 + wv;           // rows 0..255 carry all cells

    // One coalesced 140B load of the whole xy row; lanes >= XYS read slot 0.
    const int* xr = xy + ((size_t)b * NPER + r) * XYS;
    int hv = xr[lane < XYS ? lane : 0];

    int row = __builtin_amdgcn_readlane(hv, 0);   // SGPR
    int col = __builtin_amdgcn_readlane(hv, 1);
    int cnt = __builtin_amdgcn_readlane(hv, 2);
    if (row < 0) return;                          // wave-uniform scalar branch
    if (cnt > KMAX) cnt = KMAX;

    const float4* Fb4 = (const float4*)(F + (size_t)b * NPER * DFEAT);
    float4 acc = make_float4(0.f, 0.f, 0.f, 0.f);

    {   // round 1: slots 0..15, unconditional (cnt >= 1 always)
        float4 f[16];
        #pragma unroll
        for (int j = 0; j < 16; ++j) {
            int raw = __builtin_amdgcn_readlane(hv, 3 + j);  // SGPR
            int idx = (j < cnt) ? raw : 0;                   // scalar select
            f[j] = Fb4[(size_t)idx * 64 + lane];             // saddr + lane*16
        }
        #pragma unroll
        for (int j = 0; j < 16; ++j) {
            float w = (j < cnt) ? 1.f : 0.f;
            acc.x += w * f[j].x; acc.y += w * f[j].y;
            acc.z += w * f[j].z; acc.w += w * f[j].w;
        }
    }
    if (cnt > 16) {   // round 2: slots 16..31, wave-uniform skip (~50% of rows)
        float4 f[16];
        #pragma unroll
        for (int j = 0; j < 16; ++j) {
            int raw = __builtin_amdgcn_readlane(hv, 19 + j);
            int idx = (16 + j < cnt) ? raw : 0;
            f[j] = Fb4[(size_t)idx * 64 + lane];
        }
        #pragma unroll
        for (int j = 0; j < 16; ++j) {
            float w = (16 + j < cnt) ? 1.f : 0.f;
            acc.x += w * f[j].x; acc.y += w * f[j].y;
            acc.z += w * f[j].z; acc.w += w * f[j].w;
        }
    }

    float inv = 1.f / (float)(cnt > 0 ? cnt : 1);
    float4 res = make_float4(acc.x * inv, acc.y * inv, acc.z * inv, acc.w * inv);
    int cell = row * GRIDN + col;
    *(float4*)(ws + ((size_t)b * RCELLS + cell) * DFEAT + lane * 4) = res;
}

// ---------------------------------------------------------------------------
// Phase 2: transpose ws[b][cell][d] -> out[b][d][cell].
// Thread = one d. Reads coalesced (256B/wave, L2/L3-hot, XCD-matched),
// stores float4-contiguous.
// ---------------------------------------------------------------------------
__global__ __launch_bounds__(256, 4) void spp_pool_phase2(
    const float* __restrict__ ws,
    float*       __restrict__ out,
    int B)
{
    int bx = blockIdx.x;
    int b, c0;
    if ((B & 7) == 0) {
        int xcd = bx & 7;
        int s   = bx >> 3;
        b  = xcd * (B >> 3) + (s >> 2);
        c0 = (s & 3) * 64;
    } else {
        b  = bx >> 2;
        c0 = (bx & 3) * 64;
    }
    int d = threadIdx.x;

    float v[64];
    const float* wsb = ws + (size_t)b * RCELLS * DFEAT + d;
    #pragma unroll
    for (int i = 0; i < 64; ++i)
        v[i] = wsb[(size_t)(c0 + i) * DFEAT];

    float* ob = out + (size_t)b * DFEAT * RCELLS + (size_t)d * RCELLS + c0;
    #pragma unroll
    for (int i = 0; i < 16; ++i) {
        float4 q = make_float4(v[4*i], v[4*i+1], v[4*i+2], v[4*i+3]);
        *(float4*)(ob + 4 * i) = q;
    }
}

extern "C" void kernel_launch(void* const* d_in, const int* in_sizes, int n_in,
                              void* d_out, int out_size, void* d_ws, size_t ws_size,
                              hipStream_t stream) {
    const float* F   = (const float*)d_in[0];
    const int*   xy  = (const int*)d_in[1];
    float*       out = (float*)d_out;
    float*       ws  = (float*)d_ws;      // B*RCELLS*DFEAT*4 = ~16.8 MB
    int B = in_sizes[2];                  // nodes_per_graph length = 64

    hipLaunchKernelGGL(spp_pool_phase1, dim3(B * 64), dim3(256), 0, stream,
                       F, xy, ws, B);
    hipLaunchKernelGGL(spp_pool_phase2, dim3(B * 4), dim3(256), 0, stream,
                       ws, out, B);
}